// Round 1
// 310.663 us; speedup vs baseline: 1.1117x; 1.1117x over previous
//
#include <hip/hip_runtime.h>
#include <math.h>

#define NBINS 28
#define L2E 1.44269504088896340736f

#define EXP2F(x) __builtin_amdgcn_exp2f(x)
#define RCPF(x)  __builtin_amdgcn_rcpf(x)
#define SCHED_FENCE() __builtin_amdgcn_sched_barrier(0)

// workspace float offsets.  ROW-MAJOR, prescaled:
//   WS_W1[f*16+j] = W1[f][j] * -log2e     (f=0..7,  j=0..15)
//   WS_W2[k*16+j] = W2[k][j] * -log2e     (k=0..15, j=0..15)
// Row-major so each 16-float row is one 64B-aligned s_load_dwordx16:
// weights are wave-uniform -> the compiler scalarizes these loads into
// SGPRs (K$ path), eliminating the per-thread ds_read broadcast storm
// that was the 66us DS-pipe floor of the previous (LDS-staged) version.
#define WS_TBL 0    // 40 floats: ml_table[d-1] = exp(ml_mlp(d) - 0.25 d), d=1..40
#define WS_W1  64   // 128 floats, row-major, * -log2e
#define WS_B1  192  // 16, * -log2e
#define WS_W2  208  // 256 floats, row-major, * -log2e
#define WS_B2  464  // 16, * -log2e
#define WS_W3  480  // 16, * +log2e
#define WS_B3  496  // 1, * +log2e
#define WS_TOT 512

__global__ void prep_kernel(const float* __restrict__ mh_W1, const float* __restrict__ mh_b1,
                            const float* __restrict__ mh_W2, const float* __restrict__ mh_b2,
                            const float* __restrict__ mh_W3, const float* __restrict__ mh_b3,
                            const float* __restrict__ ml_W1, const float* __restrict__ ml_b1,
                            const float* __restrict__ ml_W2, const float* __restrict__ ml_b2,
                            const float* __restrict__ ml_W3, const float* __restrict__ ml_b3,
                            float* __restrict__ ws, float* __restrict__ out_bins) {
    const int t = threadIdx.x;  // 64 threads
    // W1 is [8][16] row-major in the input already; just scale.
    for (int k = t; k < 128; k += 64) ws[WS_W1 + k] = -L2E * mh_W1[k];
    for (int k = t; k < 16;  k += 64) ws[WS_B1 + k] = -L2E * mh_b1[k];
    // W2 is [16][16] row-major in the input already; just scale.
    for (int k = t; k < 256; k += 64) ws[WS_W2 + k] = -L2E * mh_W2[k];
    for (int k = t; k < 16;  k += 64) ws[WS_B2 + k] = -L2E * mh_b2[k];
    for (int k = t; k < 16;  k += 64) ws[WS_W3 + k] =  L2E * mh_W3[k];
    if (t == 0) ws[WS_B3] = L2E * mh_b3[0];

    if (t < 40) {
        const float x = (float)(t + 1);
        float h1[16], h2[16];
        #pragma unroll
        for (int j = 0; j < 16; ++j)
            h1[j] = 1.0f / (1.0f + expf(-(x * ml_W1[j] + ml_b1[j])));
        #pragma unroll
        for (int j = 0; j < 16; ++j) {
            float a = ml_b2[j];
            #pragma unroll
            for (int k = 0; k < 16; ++k) a = fmaf(h1[k], ml_W2[k * 16 + j], a);
            h2[j] = 1.0f / (1.0f + expf(-a));
        }
        float phi = ml_b3[0];
        #pragma unroll
        for (int k = 0; k < 16; ++k) phi = fmaf(h2[k], ml_W3[k], phi);
        const float sc = expf(phi - 0.25f * x);
        ws[WS_TBL + t] = sc;
        if (t < NBINS) out_bins[t] = sc;  // dl2_scores term of output 1
    }
}

// 2 rows/thread.  Weights consumed directly from global `ws` with
// wave-uniform compile-time indices -> compiler emits s_load_dwordx16
// into SGPRs; FMAs use the 1-SGPR-operand slot of v_fma_f32.  No LDS
// weight staging at all (LDS holds only the 40-entry divergent-lookup
// table and the per-wave bin accumulators).  SCHED_FENCE every 2 weight
// rows bounds in-flight scalar loads to ~32 SGPRs so the scheduler
// cannot hoist all 27 wide s_loads (SGPR file ~102).
__global__ __launch_bounds__(256) void main_kernel(
        const float4* __restrict__ x4,
        const int2* __restrict__ dl2p,
        const int2* __restrict__ ml2p,
        const float* __restrict__ ws,
        float2* __restrict__ out2,
        float* __restrict__ out_bins,
        int npair) {
    __shared__ float s_tbl[40];
    __shared__ float s_bins[4 * NBINS];
    const int tid = threadIdx.x;
    if (tid < 40) s_tbl[tid] = ws[WS_TBL + tid];
    if (tid < 4 * NBINS) s_bins[tid] = 0.0f;
    __syncthreads();

    const int p = blockIdx.x * 256 + tid;
    const bool active = (p < npair);
    const int pc = active ? p : 0;   // clamp loads; discard via `active` at store

    const float4 a0 = x4[4 * pc + 0];
    const float4 a1 = x4[4 * pc + 1];
    const float4 b0 = x4[4 * pc + 2];
    const float4 b1 = x4[4 * pc + 3];
    const int2 dl = dl2p[pc];
    const int2 ml = ml2p[pc];
    const float xf0[8] = {a0.x, a0.y, a0.z, a0.w, a1.x, a1.y, a1.z, a1.w};
    const float xf1[8] = {b0.x, b0.y, b0.z, b0.w, b1.x, b1.y, b1.z, b1.w};

    // ---- layer 1: 8 -> 16 (weights prescaled by -log2e, SGPR-resident) ----
    float u0[16], u1[16];
    #pragma unroll
    for (int j = 0; j < 16; ++j) {
        const float b = ws[WS_B1 + j];
        u0[j] = b; u1[j] = b;
    }
    SCHED_FENCE();
    #pragma unroll
    for (int f = 0; f < 8; ++f) {
        #pragma unroll
        for (int j = 0; j < 16; ++j) {
            const float w = ws[WS_W1 + f * 16 + j];
            u0[j] = fmaf(xf0[f], w, u0[j]);
            u1[j] = fmaf(xf1[f], w, u1[j]);
        }
        if (f & 1) SCHED_FENCE();
    }
    float h0[16], h1[16];
    #pragma unroll
    for (int j = 0; j < 16; ++j) {
        h0[j] = RCPF(1.0f + EXP2F(u0[j]));
        h1[j] = RCPF(1.0f + EXP2F(u1[j]));
    }

    // ---- layer 2: 16 -> 16 ----
    float v0[16], v1[16];
    #pragma unroll
    for (int j = 0; j < 16; ++j) {
        const float b = ws[WS_B2 + j];
        v0[j] = b; v1[j] = b;
    }
    SCHED_FENCE();
    #pragma unroll
    for (int k = 0; k < 16; ++k) {
        #pragma unroll
        for (int j = 0; j < 16; ++j) {
            const float w = ws[WS_W2 + k * 16 + j];
            v0[j] = fmaf(h0[k], w, v0[j]);
            v1[j] = fmaf(h1[k], w, v1[j]);
        }
        if (k & 1) SCHED_FENCE();
    }

    // ---- layer 3 + psi ----
    float phi0 = ws[WS_B3], phi1 = phi0;   // prescaled by +log2e
    #pragma unroll
    for (int j = 0; j < 16; ++j) {
        const float w3 = ws[WS_W3 + j];    // prescaled by +log2e
        phi0 = fmaf(RCPF(1.0f + EXP2F(v0[j])), w3, phi0);
        phi1 = fmaf(RCPF(1.0f + EXP2F(v1[j])), w3, phi1);
    }
    const float sc0 = EXP2F(fmaf((float)dl.x, -0.25f * L2E, phi0));
    const float sc1 = EXP2F(fmaf((float)dl.y, -0.25f * L2E, phi1));

    // ---- epilogue ----
    if (active) {
        const int i0 = min(max(dl.x, 1), 40) - 1;
        const int i1 = min(max(dl.y, 1), 40) - 1;
        const float add0 = (dl.x == ml.x) ? s_tbl[i0] : 0.0f;
        const float add1 = (dl.y == ml.y) ? s_tbl[i1] : 0.0f;
        out2[p] = make_float2(sc0 + add0, sc1 + add1);
        float* myb = &s_bins[(tid >> 6) * NBINS];
        if (dl.x >= 1 && dl.x <= NBINS) unsafeAtomicAdd(&myb[dl.x - 1], sc0);
        if (dl.y >= 1 && dl.y <= NBINS) unsafeAtomicAdd(&myb[dl.y - 1], sc1);
    }

    __syncthreads();
    if (tid < NBINS) {
        const float bsum = s_bins[tid] + s_bins[NBINS + tid] +
                           s_bins[2 * NBINS + tid] + s_bins[3 * NBINS + tid];
        unsafeAtomicAdd(&out_bins[tid], bsum);
    }
}

extern "C" void kernel_launch(void* const* d_in, const int* in_sizes, int n_in,
                              void* d_out, int out_size, void* d_ws, size_t ws_size,
                              hipStream_t stream) {
    const int n = in_sizes[0] / 8;  // N rows (even)

    const float* x_feat = (const float*)d_in[0];
    const float* mh_W1  = (const float*)d_in[1];
    const float* mh_b1  = (const float*)d_in[2];
    const float* mh_W2  = (const float*)d_in[3];
    const float* mh_b2  = (const float*)d_in[4];
    const float* mh_W3  = (const float*)d_in[5];
    const float* mh_b3  = (const float*)d_in[6];
    const float* ml_W1  = (const float*)d_in[7];
    const float* ml_b1  = (const float*)d_in[8];
    const float* ml_W2  = (const float*)d_in[9];
    const float* ml_b2  = (const float*)d_in[10];
    const float* ml_W3  = (const float*)d_in[11];
    const float* ml_b3  = (const float*)d_in[12];
    const int* del_lens = (const int*)d_in[13];
    const int* mh_len   = (const int*)d_in[14];

    float* out      = (float*)d_out;
    float* out_bins = out + n;  // last 28 elements of d_out
    float* ws       = (float*)d_ws;

    prep_kernel<<<dim3(1), dim3(64), 0, stream>>>(
        mh_W1, mh_b1, mh_W2, mh_b2, mh_W3, mh_b3,
        ml_W1, ml_b1, ml_W2, ml_b2, ml_W3, ml_b3,
        ws, out_bins);

    const int npair = n / 2;
    const int nblocks = (npair + 255) / 256;
    main_kernel<<<dim3(nblocks), dim3(256), 0, stream>>>(
        (const float4*)x_feat, (const int2*)del_lens, (const int2*)mh_len,
        ws, (float2*)out, out_bins, npair);
}